// Round 7
// baseline (2734.281 us; speedup 1.0000x reference)
//
#include <hip/hip_runtime.h>

// BiTransformer fwd: B=8,S=1024,D=1024,H=8,DH=512,R=36,V=32002, 2 layers.
// Device I/O float32. Internal GEMM operands bf16.
// gemm_t<BN>: 128xBN tile (BN=128 or 64), BK=64, 4 waves, XOR bank swizzle,
//             XCD block swizzle, global_load_lds staging. Scores kept bf16.

using u16 = unsigned short;
typedef __attribute__((ext_vector_type(8))) short bf16x8;
typedef __attribute__((ext_vector_type(4))) float f32x4;

__device__ __forceinline__ float b2f(u16 u) {
  union { unsigned int i; float f; } v; v.i = ((unsigned int)u) << 16; return v.f;
}
__device__ __forceinline__ u16 f2b(float f) {
  union { float f; unsigned int i; } v; v.f = f;
  unsigned int i = v.i;
  return (u16)((i + 0x7FFFu + ((i >> 16) & 1u)) >> 16);
}
__device__ __forceinline__ float gelu_f(float x) {
  return 0.5f * x * (1.f + erff(x * 0.70710678118654752f));
}
__device__ __forceinline__ void async16(void* lds, const void* g) {
  __builtin_amdgcn_global_load_lds((const __attribute__((address_space(1))) void*)g,
                                   (__attribute__((address_space(3))) void*)lds, 16, 0, 0);
}
__device__ __forceinline__ void storeC(float* p, float v) { *p = v; }
__device__ __forceinline__ void storeC(u16* p, float v) { *p = f2b(v); }

// ---------------- embedding (f32 in, f32 out) ----------------
__global__ __launch_bounds__(256) void embed_k(
    const int* __restrict__ words, const float* __restrict__ img,
    const float* __restrict__ emb, const float* __restrict__ id2v,
    float* __restrict__ x)
{
  __shared__ float vs[36];
  int tok = blockIdx.x, b = tok >> 10, t = threadIdx.x;
  int wd = words[tok];
  if (t < 36) vs[t] = id2v[(size_t)wd * 36 + t];
  __syncthreads();
  bool any = false;
#pragma unroll
  for (int r = 0; r < 36; ++r) any = any || (vs[r] != 0.f);
#pragma unroll
  for (int i = 0; i < 4; ++i) {
    int d = t + (i << 8);
    float acc = 0.f;
    for (int r = 0; r < 36; ++r) {
      float vv = vs[r];
      if (vv != 0.f) acc += vv * img[((size_t)(b * 36 + r) << 10) + d];
    }
    float te = any ? 0.f : emb[((size_t)wd << 10) + d];
    x[((size_t)tok << 10) + d] = te + acc;
  }
}

// ---------------- layernorm (f32 in, bf16 out), D=1024 ----------------
__global__ __launch_bounds__(256) void ln_k(
    const float* __restrict__ x, u16* __restrict__ out,
    const float* __restrict__ g, const float* __restrict__ bb)
{
  __shared__ float red[4];
  int row = blockIdx.x, t = threadIdx.x;
  const float* xr = x + ((size_t)row << 10);
  float v[4], s = 0.f;
#pragma unroll
  for (int i = 0; i < 4; ++i) { v[i] = xr[t + (i << 8)]; s += v[i]; }
#pragma unroll
  for (int o = 32; o; o >>= 1) s += __shfl_xor(s, o, 64);
  if ((t & 63) == 0) red[t >> 6] = s;
  __syncthreads();
  s = red[0] + red[1] + red[2] + red[3];
  float mean = s * 0.0009765625f;
  float q = 0.f;
#pragma unroll
  for (int i = 0; i < 4; ++i) { float d = v[i] - mean; q += d * d; }
  __syncthreads();
#pragma unroll
  for (int o = 32; o; o >>= 1) q += __shfl_xor(q, o, 64);
  if ((t & 63) == 0) red[t >> 6] = q;
  __syncthreads();
  q = red[0] + red[1] + red[2] + red[3];
  float rstd = rsqrtf(q * 0.0009765625f + 1e-5f);
  u16* orow = out + ((size_t)row << 10);
#pragma unroll
  for (int i = 0; i < 4; ++i) {
    int d = t + (i << 8);
    orow[d] = f2b((v[i] - mean) * rstd * g[d] + bb[d]);
  }
}

// ------------- shifted softmax on bf16 scores: p = e^(s-m)/(1+sum), cols=1024 -------------
__global__ __launch_bounds__(256) void sm_k(const u16* __restrict__ S, u16* __restrict__ P)
{
  __shared__ float red[4];
  size_t row = blockIdx.x;
  int t = threadIdx.x;
  const u16* sr = S + (row << 10);
  ushort4 sv = *(const ushort4*)(sr + (t << 2));
  float v[4] = { b2f(sv.x), b2f(sv.y), b2f(sv.z), b2f(sv.w) };
  float m = fmaxf(fmaxf(v[0], v[1]), fmaxf(v[2], v[3]));
#pragma unroll
  for (int o = 32; o; o >>= 1) m = fmaxf(m, __shfl_xor(m, o, 64));
  if ((t & 63) == 0) red[t >> 6] = m;
  __syncthreads();
  m = fmaxf(fmaxf(red[0], red[1]), fmaxf(red[2], red[3]));
  float e[4], s = 0.f;
#pragma unroll
  for (int i = 0; i < 4; ++i) { e[i] = __expf(v[i] - m); s += e[i]; }
  __syncthreads();
#pragma unroll
  for (int o = 32; o; o >>= 1) s += __shfl_xor(s, o, 64);
  if ((t & 63) == 0) red[t >> 6] = s;
  __syncthreads();
  s = red[0] + red[1] + red[2] + red[3];
  float inv = 1.f / (1.f + s);
  ushort4 pv;
  pv.x = f2b(e[0] * inv); pv.y = f2b(e[1] * inv);
  pv.z = f2b(e[2] * inv); pv.w = f2b(e[3] * inv);
  *(ushort4*)(P + (row << 10) + (t << 2)) = pv;
}

// ------------- weight transpose + f32->bf16, 64x64 tiles -------------
__global__ __launch_bounds__(256) void tr_k(
    const float* __restrict__ src, u16* __restrict__ dst, int ls, int ld)
{
  __shared__ u16 tile[64][65];
  int c0 = blockIdx.x << 6, r0 = blockIdx.y << 6;
  int tx = threadIdx.x & 63, ty0 = threadIdx.x >> 6;
#pragma unroll
  for (int i = 0; i < 16; ++i) {
    int ty = (ty0 << 4) + i;
    tile[ty][tx] = f2b(src[(size_t)(r0 + ty) * ls + (c0 + tx)]);
  }
  __syncthreads();
#pragma unroll
  for (int i = 0; i < 16; ++i) {
    int ty = (ty0 << 4) + i;
    dst[(size_t)(c0 + ty) * ld + (r0 + tx)] = tile[tx][ty];
  }
}

// ======== gemm_t<BN>: C = act(scale*A@Bt^T + bias) [+resid], 128xBN tile ========
// BK=64, 4 waves (2Mx2N), wave tile 64 x BN/2, XOR chunk swizzle (chunk ^= row&7),
// XCD-aware bijective block swizzle, global_load_lds staging.
// A:(M,K) lda; Bt:(N,K) ldb; C:(M,N) ldc.
// z: z_op = (gflag ? zbase : 0) + blockIdx.z; off = (z/zdiv)*S1 + (z%zdiv)*S2.
// BIAS: 0 none, 1 per-col (f32), 2 per-row (f32).
template <typename CT, int ACT, int BIAS, int RESID, int BN>
__global__ __launch_bounds__(256, (BN == 128) ? 5 : 6) void gemm_t(
    const u16* __restrict__ A, const u16* __restrict__ Bt,
    CT* __restrict__ C, const float* __restrict__ bias,
    const float* __restrict__ resid,
    int M, int N, int K, int lda, int ldb, int ldc, float scale,
    int zbase, int zdiv, int ga, int gb, int gc,
    long long aS1, long long aS2, long long bS1, long long bS2,
    long long cS1, long long cS2)
{
  constexpr int NACC = BN / 32;           // accum tiles per wave in N
  __shared__ u16 lA[128 * 64];
  __shared__ u16 lB[BN * 64];
  // XCD-aware bijective remap of the (x,y) grid
  const int nwg = gridDim.x * gridDim.y;
  const int id = blockIdx.y * gridDim.x + blockIdx.x;
  const int qq = nwg >> 3, rr8 = nwg & 7;
  const int xcd = id & 7, off = id >> 3;
  const int swz = (xcd < rr8 ? xcd * (qq + 1) : rr8 * (qq + 1) + (xcd - rr8) * qq) + off;
  const int bx = swz % gridDim.x, by = swz / gridDim.x;

  long long lz = blockIdx.z;
  long long gz = zbase + lz;
  long long zA = ga ? gz : lz, zB = gb ? gz : lz, zC = gc ? gz : lz;
  size_t aOff = (size_t)((zA / zdiv) * aS1 + (zA % zdiv) * aS2);
  size_t bOff = (size_t)((zB / zdiv) * bS1 + (zB % zdiv) * bS2);
  size_t cOff = (size_t)((zC / zdiv) * cS1 + (zC % zdiv) * cS2);
  const int m0 = by << 7, n0 = bx * BN;
  const int tid = threadIdx.x, lane = tid & 63, w = tid >> 6;
  const int wm = w >> 1, wn = w & 1;         // 2x2 wave grid
  const int srow8 = lane >> 3;               // staging row within 8-row slice
  const int schunk = (lane & 7) ^ srow8;     // inverse-swizzled source chunk
  const int fr = lane & 15, hi = lane >> 4;

  f32x4 acc[4][NACC];
#pragma unroll
  for (int mi = 0; mi < 4; ++mi)
#pragma unroll
    for (int ni = 0; ni < NACC; ++ni) acc[mi][ni] = 0.f;

  const u16* Ab = A + aOff;
  const u16* Bb = Bt + bOff;

  for (int k0 = 0; k0 < K; k0 += 64) {
#pragma unroll
    for (int s = 0; s < 4; ++s) {
      const int rb = (s << 5) + (w << 3);  // rows rb..rb+7
      async16(&lA[rb << 6], Ab + (size_t)(m0 + rb + srow8) * lda + (k0 + (schunk << 3)));
    }
#pragma unroll
    for (int s = 0; s < BN / 32; ++s) {
      const int rb = (s << 5) + (w << 3);
      async16(&lB[rb << 6], Bb + (size_t)(n0 + rb + srow8) * ldb + (k0 + (schunk << 3)));
    }
    __syncthreads();  // drains vmcnt -> tile visible
#pragma unroll
    for (int ks = 0; ks < 2; ++ks) {
      const int q = (ks << 2) + hi;  // K-chunk 0..7
      bf16x8 a8[4], b8[NACC];
#pragma unroll
      for (int mi = 0; mi < 4; ++mi) {
        const int R = (wm << 6) + (mi << 4) + fr;
        a8[mi] = *(const bf16x8*)&lA[(R << 6) + ((q ^ (R & 7)) << 3)];
      }
#pragma unroll
      for (int ni = 0; ni < NACC; ++ni) {
        const int R = wn * (BN / 2) + (ni << 4) + fr;
        b8[ni] = *(const bf16x8*)&lB[(R << 6) + ((q ^ (R & 7)) << 3)];
      }
#pragma unroll
      for (int mi = 0; mi < 4; ++mi)
#pragma unroll
        for (int ni = 0; ni < NACC; ++ni)
          acc[mi][ni] = __builtin_amdgcn_mfma_f32_16x16x32_bf16(a8[mi], b8[ni], acc[mi][ni], 0, 0, 0);
    }
    __syncthreads();  // reads done before next stage overwrites
  }

  const int r4 = hi << 2, cc = fr;
#pragma unroll
  for (int mi = 0; mi < 4; ++mi) {
#pragma unroll
    for (int ni = 0; ni < NACC; ++ni) {
      const int col = n0 + wn * (BN / 2) + (ni << 4) + cc;
      float bcol = 0.f;
      if (BIAS == 1) bcol = bias[col];
#pragma unroll
      for (int j = 0; j < 4; ++j) {
        const int row = m0 + (wm << 6) + (mi << 4) + r4 + j;
        float v = acc[mi][ni][j] * scale + bcol;
        if (BIAS == 2) v += bias[row];
        if (ACT == 1) v = gelu_f(v);
        const size_t idx = cOff + (size_t)row * ldc + col;
        if (RESID) v += resid[idx];
        storeC(&C[idx], v);
      }
    }
  }
}

extern "C" void kernel_launch(void* const* d_in, const int* in_sizes, int n_in,
                              void* d_out, int out_size, void* d_ws, size_t ws_size,
                              hipStream_t stream)
{
  (void)in_sizes; (void)n_in; (void)out_size;
  const int*   pre_words = (const int*)d_in[0];
  const float* img  = (const float*)d_in[1];
  const float* emb  = (const float*)d_in[2];
  const float* id2v = (const float*)d_in[3];
  const float* wq = (const float*)d_in[4];  const float* bq = (const float*)d_in[5];
  const float* wk = (const float*)d_in[6];  const float* bk = (const float*)d_in[7];
  const float* wv = (const float*)d_in[8];  const float* bv = (const float*)d_in[9];
  const float* wo = (const float*)d_in[10]; const float* bo = (const float*)d_in[11];
  const float* w1 = (const float*)d_in[12]; const float* b1 = (const float*)d_in[13];
  const float* w2 = (const float*)d_in[14]; const float* b2 = (const float*)d_in[15];
  const float* ln1g = (const float*)d_in[16]; const float* ln1b = (const float*)d_in[17];
  const float* ln2g = (const float*)d_in[18]; const float* ln2b = (const float*)d_in[19];

  const size_t FIXED = 88080384 + (size_t)(1 << 16);
  int g = 1;
  for (int c = 8; c >= 1; c >>= 1)
    if (FIXED + (size_t)c * 33554432 + 4194304 <= ws_size) { g = c; break; }
  int nc = 1;
  int ncmax = 8 * g > 32 ? 32 : 8 * g;
  for (int c = ncmax; c >= 1; c >>= 1)
    if (FIXED + (size_t)g * 33554432 + (size_t)c * 4194304 <= ws_size) { nc = c; break; }

  char* p = (char*)d_ws;
  auto alloc = [&](size_t bytes) -> void* {
    void* r = (void*)p; p += (bytes + 255) & ~(size_t)255; return r;
  };
  float* x  = (float*)alloc((size_t)8192 * 1024 * 4);     // residual f32 (32MB)
  u16* h    = (u16*)alloc((size_t)8192 * 1024 * 2);       // LN output (16MB)
  u16* Qg   = (u16*)alloc((size_t)g * 1024 * 4096 * 2);   // group Q
  u16* Og   = (u16*)alloc((size_t)g * 1024 * 4096 * 2);   // group O
  u16* ff   = Qg;                                         // FFN mid reuses Qg[+Og]
  u16* Kg   = (u16*)alloc((size_t)g * 1024 * 4096 * 2);   // group K
  u16* Vtg  = (u16*)alloc((size_t)g * 4096 * 1024 * 2);   // group V^T (per batch (HD,S))
  u16* wqt  = (u16*)alloc((size_t)4096 * 1024 * 2);
  u16* wkt  = (u16*)alloc((size_t)4096 * 1024 * 2);
  u16* wvt  = (u16*)alloc((size_t)4096 * 1024 * 2);
  u16* wot  = (u16*)alloc((size_t)1024 * 4096 * 2);
  u16* w1t  = (u16*)alloc((size_t)1024 * 1024 * 2);
  u16* w2t  = (u16*)alloc((size_t)1024 * 1024 * 2);
  u16* Sc   = (u16*)alloc((size_t)nc << 21);   // nc * 1M bf16 scores
  u16* Pp   = (u16*)alloc((size_t)nc << 21);   // nc * 1M bf16 probs

  embed_k<<<8192, 256, 0, stream>>>(pre_words, img, emb, id2v, x);

  const float qk_scale = 0.044194173824159216f;  // 1/sqrt(512)
  for (int L = 0; L < 2; ++L) {
    const float* WQ = wq + (size_t)L * 1024 * 4096;
    const float* WK = wk + (size_t)L * 1024 * 4096;
    const float* WV = wv + (size_t)L * 1024 * 4096;
    const float* WO = wo + (size_t)L * 4096 * 1024;
    const float* W1 = w1 + (size_t)L * 1024 * 1024;
    const float* W2 = w2 + (size_t)L * 1024 * 1024;

    tr_k<<<dim3(64, 16), 256, 0, stream>>>(WQ, wqt, 4096, 1024);
    tr_k<<<dim3(64, 16), 256, 0, stream>>>(WK, wkt, 4096, 1024);
    tr_k<<<dim3(64, 16), 256, 0, stream>>>(WV, wvt, 4096, 1024);
    tr_k<<<dim3(16, 64), 256, 0, stream>>>(WO, wot, 1024, 4096);
    tr_k<<<dim3(16, 16), 256, 0, stream>>>(W1, w1t, 1024, 1024);
    tr_k<<<dim3(16, 16), 256, 0, stream>>>(W2, w2t, 1024, 1024);

    ln_k<<<8192, 256, 0, stream>>>(x, h, ln1g + L * 1024, ln1b + L * 1024);

    for (int g0 = 0; g0 < 8; g0 += g) {
      const u16* hg = h + (size_t)g0 * 1048576;
      const int Mg = 1024 * g;
      // Qg / Kg = h_g @ w + bias : (Mg, 4096)
      gemm_t<u16, 0, 1, 0, 128><<<dim3(32, Mg >> 7), 256, 0, stream>>>(
          hg, wqt, Qg, bq + (size_t)L * 4096, nullptr,
          Mg, 4096, 1024, 1024, 1024, 4096, 1.f,
          0, 1, 0, 0, 0, 0, 0, 0, 0, 0, 0);
      gemm_t<u16, 0, 1, 0, 128><<<dim3(32, Mg >> 7), 256, 0, stream>>>(
          hg, wkt, Kg, bk + (size_t)L * 4096, nullptr,
          Mg, 4096, 1024, 1024, 1024, 4096, 1.f,
          0, 1, 0, 0, 0, 0, 0, 0, 0, 0, 0);
      // Vtg[b][hd][s] = (h_b @ wv + bv)^T : A=wvt, B=h_b, row-bias, z=batch
      gemm_t<u16, 0, 2, 0, 128><<<dim3(8, 32, g), 256, 0, stream>>>(
          wvt, h, Vtg, bv + (size_t)L * 4096, nullptr,
          4096, 1024, 1024, 1024, 1024, 1024, 1.f,
          g0, 1, 0, 1, 0, 0, 0, 1048576LL, 0, 4194304LL, 0);
      // attention over 8g (b,h) pairs, chunks of nc
      for (int c0 = 0; c0 < 8 * g; c0 += nc) {
        gemm_t<u16, 0, 0, 0, 128><<<dim3(8, 8, nc), 256, 0, stream>>>(
            Qg, Kg, Sc, nullptr, nullptr,
            1024, 1024, 512, 4096, 4096, 1024, qk_scale,
            c0, 8, 1, 1, 0,
            4194304LL, 512LL, 4194304LL, 512LL, 8388608LL, 1048576LL);
        sm_k<<<nc << 10, 256, 0, stream>>>(Sc, Pp);
        gemm_t<u16, 0, 0, 0, 128><<<dim3(4, 8, nc), 256, 0, stream>>>(
            Pp, Vtg, Og, nullptr, nullptr,
            1024, 512, 1024, 1024, 1024, 4096, 1.f,
            c0, 8, 0, 1, 1,
            8388608LL, 1048576LL, 4194304LL, 524288LL, 4194304LL, 512LL);
      }
      // x_g += O_g @ wo + bo  (BN=64 -> 1024 blocks)
      gemm_t<float, 0, 1, 1, 64><<<dim3(16, Mg >> 7), 256, 0, stream>>>(
          Og, wot, x + (size_t)g0 * 1048576, bo + (size_t)L * 1024,
          x + (size_t)g0 * 1048576,
          Mg, 1024, 4096, 4096, 4096, 1024, 1.f,
          0, 1, 0, 0, 0, 0, 0, 0, 0, 0, 0);
    }

    ln_k<<<8192, 256, 0, stream>>>(x, h, ln2g + L * 1024, ln2b + L * 1024);

    // ff = gelu(h @ w1 + b1)  (BN=64)
    gemm_t<u16, 1, 1, 0, 64><<<dim3(16, 64), 256, 0, stream>>>(
        h, w1t, ff, b1 + (size_t)L * 1024, nullptr,
        8192, 1024, 1024, 1024, 1024, 1024, 1.f,
        0, 1, 0, 0, 0, 0, 0, 0, 0, 0, 0);
    // x += ff @ w2 + b2  (last layer writes d_out directly)
    float* cdst = (L == 1) ? (float*)d_out : x;
    gemm_t<float, 0, 1, 1, 64><<<dim3(16, 64), 256, 0, stream>>>(
        ff, w2t, cdst, b2 + (size_t)L * 1024, x,
        8192, 1024, 1024, 1024, 1024, 1024, 1.f,
        0, 1, 0, 0, 0, 0, 0, 0, 0, 0, 0);
  }
}

// Round 8
// 1524.288 us; speedup vs baseline: 1.7938x; 1.7938x over previous
//
#include <hip/hip_runtime.h>

// BiTransformer fwd: B=8,S=1024,D=1024,H=8,DH=512,R=36,V=32002, 2 layers.
// Device I/O float32. Internal GEMM operands bf16.
// gemm_t<BN>: 128xBN tile (BN=128 or 64), BK=64, 4 waves, XOR bank swizzle,
//             XCD block swizzle, global_load_lds staging. launch_bounds(256,4)
//             -- (256,5/6) in R7 forced VGPR 64->48 and spilled acc to scratch
//                (465MB WRITE_SIZE/dispatch). Do not raise without VGPR slack.

using u16 = unsigned short;
typedef __attribute__((ext_vector_type(8))) short bf16x8;
typedef __attribute__((ext_vector_type(4))) float f32x4;

__device__ __forceinline__ float b2f(u16 u) {
  union { unsigned int i; float f; } v; v.i = ((unsigned int)u) << 16; return v.f;
}
__device__ __forceinline__ u16 f2b(float f) {
  union { float f; unsigned int i; } v; v.f = f;
  unsigned int i = v.i;
  return (u16)((i + 0x7FFFu + ((i >> 16) & 1u)) >> 16);
}
__device__ __forceinline__ float gelu_f(float x) {
  return 0.5f * x * (1.f + erff(x * 0.70710678118654752f));
}
__device__ __forceinline__ void async16(void* lds, const void* g) {
  __builtin_amdgcn_global_load_lds((const __attribute__((address_space(1))) void*)g,
                                   (__attribute__((address_space(3))) void*)lds, 16, 0, 0);
}
__device__ __forceinline__ void storeC(float* p, float v) { *p = v; }
__device__ __forceinline__ void storeC(u16* p, float v) { *p = f2b(v); }

// ---------------- embedding (f32 in, f32 out) ----------------
__global__ __launch_bounds__(256) void embed_k(
    const int* __restrict__ words, const float* __restrict__ img,
    const float* __restrict__ emb, const float* __restrict__ id2v,
    float* __restrict__ x)
{
  __shared__ float vs[36];
  int tok = blockIdx.x, b = tok >> 10, t = threadIdx.x;
  int wd = words[tok];
  if (t < 36) vs[t] = id2v[(size_t)wd * 36 + t];
  __syncthreads();
  bool any = false;
#pragma unroll
  for (int r = 0; r < 36; ++r) any = any || (vs[r] != 0.f);
#pragma unroll
  for (int i = 0; i < 4; ++i) {
    int d = t + (i << 8);
    float acc = 0.f;
    for (int r = 0; r < 36; ++r) {
      float vv = vs[r];
      if (vv != 0.f) acc += vv * img[((size_t)(b * 36 + r) << 10) + d];
    }
    float te = any ? 0.f : emb[((size_t)wd << 10) + d];
    x[((size_t)tok << 10) + d] = te + acc;
  }
}

// ---------------- layernorm (f32 in, bf16 out), D=1024 ----------------
__global__ __launch_bounds__(256) void ln_k(
    const float* __restrict__ x, u16* __restrict__ out,
    const float* __restrict__ g, const float* __restrict__ bb)
{
  __shared__ float red[4];
  int row = blockIdx.x, t = threadIdx.x;
  const float* xr = x + ((size_t)row << 10);
  float v[4], s = 0.f;
#pragma unroll
  for (int i = 0; i < 4; ++i) { v[i] = xr[t + (i << 8)]; s += v[i]; }
#pragma unroll
  for (int o = 32; o; o >>= 1) s += __shfl_xor(s, o, 64);
  if ((t & 63) == 0) red[t >> 6] = s;
  __syncthreads();
  s = red[0] + red[1] + red[2] + red[3];
  float mean = s * 0.0009765625f;
  float q = 0.f;
#pragma unroll
  for (int i = 0; i < 4; ++i) { float d = v[i] - mean; q += d * d; }
  __syncthreads();
#pragma unroll
  for (int o = 32; o; o >>= 1) q += __shfl_xor(q, o, 64);
  if ((t & 63) == 0) red[t >> 6] = q;
  __syncthreads();
  q = red[0] + red[1] + red[2] + red[3];
  float rstd = rsqrtf(q * 0.0009765625f + 1e-5f);
  u16* orow = out + ((size_t)row << 10);
#pragma unroll
  for (int i = 0; i < 4; ++i) {
    int d = t + (i << 8);
    orow[d] = f2b((v[i] - mean) * rstd * g[d] + bb[d]);
  }
}

// ------------- shifted softmax on bf16 scores: p = e^(s-m)/(1+sum), cols=1024 -------------
__global__ __launch_bounds__(256) void sm_k(const u16* __restrict__ S, u16* __restrict__ P)
{
  __shared__ float red[4];
  size_t row = blockIdx.x;
  int t = threadIdx.x;
  const u16* sr = S + (row << 10);
  ushort4 sv = *(const ushort4*)(sr + (t << 2));
  float v[4] = { b2f(sv.x), b2f(sv.y), b2f(sv.z), b2f(sv.w) };
  float m = fmaxf(fmaxf(v[0], v[1]), fmaxf(v[2], v[3]));
#pragma unroll
  for (int o = 32; o; o >>= 1) m = fmaxf(m, __shfl_xor(m, o, 64));
  if ((t & 63) == 0) red[t >> 6] = m;
  __syncthreads();
  m = fmaxf(fmaxf(red[0], red[1]), fmaxf(red[2], red[3]));
  float e[4], s = 0.f;
#pragma unroll
  for (int i = 0; i < 4; ++i) { e[i] = __expf(v[i] - m); s += e[i]; }
  __syncthreads();
#pragma unroll
  for (int o = 32; o; o >>= 1) s += __shfl_xor(s, o, 64);
  if ((t & 63) == 0) red[t >> 6] = s;
  __syncthreads();
  s = red[0] + red[1] + red[2] + red[3];
  float inv = 1.f / (1.f + s);
  ushort4 pv;
  pv.x = f2b(e[0] * inv); pv.y = f2b(e[1] * inv);
  pv.z = f2b(e[2] * inv); pv.w = f2b(e[3] * inv);
  *(ushort4*)(P + (row << 10) + (t << 2)) = pv;
}

// ------------- weight transpose + f32->bf16, 64x64 tiles -------------
__global__ __launch_bounds__(256) void tr_k(
    const float* __restrict__ src, u16* __restrict__ dst, int ls, int ld)
{
  __shared__ u16 tile[64][65];
  int c0 = blockIdx.x << 6, r0 = blockIdx.y << 6;
  int tx = threadIdx.x & 63, ty0 = threadIdx.x >> 6;
#pragma unroll
  for (int i = 0; i < 16; ++i) {
    int ty = (ty0 << 4) + i;
    tile[ty][tx] = f2b(src[(size_t)(r0 + ty) * ls + (c0 + tx)]);
  }
  __syncthreads();
#pragma unroll
  for (int i = 0; i < 16; ++i) {
    int ty = (ty0 << 4) + i;
    dst[(size_t)(c0 + ty) * ld + (r0 + tx)] = tile[tx][ty];
  }
}

// ======== gemm_t<BN>: C = act(scale*A@Bt^T + bias) [+resid], 128xBN tile ========
// BK=64, 4 waves (2Mx2N), wave tile 64 x BN/2, XOR chunk swizzle (chunk ^= row&7),
// XCD-aware bijective block swizzle, global_load_lds staging.
// A:(M,K) lda; Bt:(N,K) ldb; C:(M,N) ldc.
// z: z_op = (gflag ? zbase : 0) + blockIdx.z; off = (z/zdiv)*S1 + (z%zdiv)*S2.
// BIAS: 0 none, 1 per-col (f32), 2 per-row (f32).
template <typename CT, int ACT, int BIAS, int RESID, int BN>
__global__ __launch_bounds__(256, 4) void gemm_t(
    const u16* __restrict__ A, const u16* __restrict__ Bt,
    CT* __restrict__ C, const float* __restrict__ bias,
    const float* __restrict__ resid,
    int M, int N, int K, int lda, int ldb, int ldc, float scale,
    int zbase, int zdiv, int ga, int gb, int gc,
    long long aS1, long long aS2, long long bS1, long long bS2,
    long long cS1, long long cS2)
{
  constexpr int NACC = BN / 32;           // accum tiles per wave in N
  __shared__ u16 lA[128 * 64];
  __shared__ u16 lB[BN * 64];
  // XCD-aware bijective remap of the (x,y) grid
  const int nwg = gridDim.x * gridDim.y;
  const int id = blockIdx.y * gridDim.x + blockIdx.x;
  const int qq = nwg >> 3, rr8 = nwg & 7;
  const int xcd = id & 7, off = id >> 3;
  const int swz = (xcd < rr8 ? xcd * (qq + 1) : rr8 * (qq + 1) + (xcd - rr8) * qq) + off;
  const int bx = swz % gridDim.x, by = swz / gridDim.x;

  long long lz = blockIdx.z;
  long long gz = zbase + lz;
  long long zA = ga ? gz : lz, zB = gb ? gz : lz, zC = gc ? gz : lz;
  size_t aOff = (size_t)((zA / zdiv) * aS1 + (zA % zdiv) * aS2);
  size_t bOff = (size_t)((zB / zdiv) * bS1 + (zB % zdiv) * bS2);
  size_t cOff = (size_t)((zC / zdiv) * cS1 + (zC % zdiv) * cS2);
  const int m0 = by << 7, n0 = bx * BN;
  const int tid = threadIdx.x, lane = tid & 63, w = tid >> 6;
  const int wm = w >> 1, wn = w & 1;         // 2x2 wave grid
  const int srow8 = lane >> 3;               // staging row within 8-row slice
  const int schunk = (lane & 7) ^ srow8;     // inverse-swizzled source chunk
  const int fr = lane & 15, hi = lane >> 4;

  f32x4 acc[4][NACC];
#pragma unroll
  for (int mi = 0; mi < 4; ++mi)
#pragma unroll
    for (int ni = 0; ni < NACC; ++ni) acc[mi][ni] = 0.f;

  const u16* Ab = A + aOff;
  const u16* Bb = Bt + bOff;

  for (int k0 = 0; k0 < K; k0 += 64) {
#pragma unroll
    for (int s = 0; s < 4; ++s) {
      const int rb = (s << 5) + (w << 3);  // rows rb..rb+7
      async16(&lA[rb << 6], Ab + (size_t)(m0 + rb + srow8) * lda + (k0 + (schunk << 3)));
    }
#pragma unroll
    for (int s = 0; s < BN / 32; ++s) {
      const int rb = (s << 5) + (w << 3);
      async16(&lB[rb << 6], Bb + (size_t)(n0 + rb + srow8) * ldb + (k0 + (schunk << 3)));
    }
    __syncthreads();  // drains vmcnt -> tile visible
#pragma unroll
    for (int ks = 0; ks < 2; ++ks) {
      const int q = (ks << 2) + hi;  // K-chunk 0..7
      bf16x8 a8[4], b8[NACC];
#pragma unroll
      for (int mi = 0; mi < 4; ++mi) {
        const int R = (wm << 6) + (mi << 4) + fr;
        a8[mi] = *(const bf16x8*)&lA[(R << 6) + ((q ^ (R & 7)) << 3)];
      }
#pragma unroll
      for (int ni = 0; ni < NACC; ++ni) {
        const int R = wn * (BN / 2) + (ni << 4) + fr;
        b8[ni] = *(const bf16x8*)&lB[(R << 6) + ((q ^ (R & 7)) << 3)];
      }
#pragma unroll
      for (int mi = 0; mi < 4; ++mi)
#pragma unroll
        for (int ni = 0; ni < NACC; ++ni)
          acc[mi][ni] = __builtin_amdgcn_mfma_f32_16x16x32_bf16(a8[mi], b8[ni], acc[mi][ni], 0, 0, 0);
    }
    __syncthreads();  // reads done before next stage overwrites
  }

  const int r4 = hi << 2, cc = fr;
#pragma unroll
  for (int mi = 0; mi < 4; ++mi) {
#pragma unroll
    for (int ni = 0; ni < NACC; ++ni) {
      const int col = n0 + wn * (BN / 2) + (ni << 4) + cc;
      float bcol = 0.f;
      if (BIAS == 1) bcol = bias[col];
#pragma unroll
      for (int j = 0; j < 4; ++j) {
        const int row = m0 + (wm << 6) + (mi << 4) + r4 + j;
        float v = acc[mi][ni][j] * scale + bcol;
        if (BIAS == 2) v += bias[row];
        if (ACT == 1) v = gelu_f(v);
        const size_t idx = cOff + (size_t)row * ldc + col;
        if (RESID) v += resid[idx];
        storeC(&C[idx], v);
      }
    }
  }
}

extern "C" void kernel_launch(void* const* d_in, const int* in_sizes, int n_in,
                              void* d_out, int out_size, void* d_ws, size_t ws_size,
                              hipStream_t stream)
{
  (void)in_sizes; (void)n_in; (void)out_size;
  const int*   pre_words = (const int*)d_in[0];
  const float* img  = (const float*)d_in[1];
  const float* emb  = (const float*)d_in[2];
  const float* id2v = (const float*)d_in[3];
  const float* wq = (const float*)d_in[4];  const float* bq = (const float*)d_in[5];
  const float* wk = (const float*)d_in[6];  const float* bk = (const float*)d_in[7];
  const float* wv = (const float*)d_in[8];  const float* bv = (const float*)d_in[9];
  const float* wo = (const float*)d_in[10]; const float* bo = (const float*)d_in[11];
  const float* w1 = (const float*)d_in[12]; const float* b1 = (const float*)d_in[13];
  const float* w2 = (const float*)d_in[14]; const float* b2 = (const float*)d_in[15];
  const float* ln1g = (const float*)d_in[16]; const float* ln1b = (const float*)d_in[17];
  const float* ln2g = (const float*)d_in[18]; const float* ln2b = (const float*)d_in[19];

  const size_t FIXED = 88080384 + (size_t)(1 << 16);
  int g = 1;
  for (int c = 8; c >= 1; c >>= 1)
    if (FIXED + (size_t)c * 33554432 + 4194304 <= ws_size) { g = c; break; }
  int nc = 1;
  int ncmax = 8 * g > 32 ? 32 : 8 * g;
  for (int c = ncmax; c >= 1; c >>= 1)
    if (FIXED + (size_t)g * 33554432 + (size_t)c * 4194304 <= ws_size) { nc = c; break; }

  char* p = (char*)d_ws;
  auto alloc = [&](size_t bytes) -> void* {
    void* r = (void*)p; p += (bytes + 255) & ~(size_t)255; return r;
  };
  float* x  = (float*)alloc((size_t)8192 * 1024 * 4);     // residual f32 (32MB)
  u16* h    = (u16*)alloc((size_t)8192 * 1024 * 2);       // LN output (16MB)
  u16* Qg   = (u16*)alloc((size_t)g * 1024 * 4096 * 2);   // group Q
  u16* Og   = (u16*)alloc((size_t)g * 1024 * 4096 * 2);   // group O
  u16* ff   = Qg;                                         // FFN mid reuses Qg[+Og]
  u16* Kg   = (u16*)alloc((size_t)g * 1024 * 4096 * 2);   // group K
  u16* Vtg  = (u16*)alloc((size_t)g * 4096 * 1024 * 2);   // group V^T (per batch (HD,S))
  u16* wqt  = (u16*)alloc((size_t)4096 * 1024 * 2);
  u16* wkt  = (u16*)alloc((size_t)4096 * 1024 * 2);
  u16* wvt  = (u16*)alloc((size_t)4096 * 1024 * 2);
  u16* wot  = (u16*)alloc((size_t)1024 * 4096 * 2);
  u16* w1t  = (u16*)alloc((size_t)1024 * 1024 * 2);
  u16* w2t  = (u16*)alloc((size_t)1024 * 1024 * 2);
  u16* Sc   = (u16*)alloc((size_t)nc << 21);   // nc * 1M bf16 scores
  u16* Pp   = (u16*)alloc((size_t)nc << 21);   // nc * 1M bf16 probs

  embed_k<<<8192, 256, 0, stream>>>(pre_words, img, emb, id2v, x);

  const float qk_scale = 0.044194173824159216f;  // 1/sqrt(512)
  for (int L = 0; L < 2; ++L) {
    const float* WQ = wq + (size_t)L * 1024 * 4096;
    const float* WK = wk + (size_t)L * 1024 * 4096;
    const float* WV = wv + (size_t)L * 1024 * 4096;
    const float* WO = wo + (size_t)L * 4096 * 1024;
    const float* W1 = w1 + (size_t)L * 1024 * 1024;
    const float* W2 = w2 + (size_t)L * 1024 * 1024;

    tr_k<<<dim3(64, 16), 256, 0, stream>>>(WQ, wqt, 4096, 1024);
    tr_k<<<dim3(64, 16), 256, 0, stream>>>(WK, wkt, 4096, 1024);
    tr_k<<<dim3(64, 16), 256, 0, stream>>>(WV, wvt, 4096, 1024);
    tr_k<<<dim3(16, 64), 256, 0, stream>>>(WO, wot, 1024, 4096);
    tr_k<<<dim3(16, 16), 256, 0, stream>>>(W1, w1t, 1024, 1024);
    tr_k<<<dim3(16, 16), 256, 0, stream>>>(W2, w2t, 1024, 1024);

    ln_k<<<8192, 256, 0, stream>>>(x, h, ln1g + L * 1024, ln1b + L * 1024);

    for (int g0 = 0; g0 < 8; g0 += g) {
      const u16* hg = h + (size_t)g0 * 1048576;
      const int Mg = 1024 * g;
      // Qg / Kg = h_g @ w + bias : (Mg, 4096)
      gemm_t<u16, 0, 1, 0, 128><<<dim3(32, Mg >> 7), 256, 0, stream>>>(
          hg, wqt, Qg, bq + (size_t)L * 4096, nullptr,
          Mg, 4096, 1024, 1024, 1024, 4096, 1.f,
          0, 1, 0, 0, 0, 0, 0, 0, 0, 0, 0);
      gemm_t<u16, 0, 1, 0, 128><<<dim3(32, Mg >> 7), 256, 0, stream>>>(
          hg, wkt, Kg, bk + (size_t)L * 4096, nullptr,
          Mg, 4096, 1024, 1024, 1024, 4096, 1.f,
          0, 1, 0, 0, 0, 0, 0, 0, 0, 0, 0);
      // Vtg[b][hd][s] = (h_b @ wv + bv)^T : A=wvt, B=h_b, row-bias, z=batch
      gemm_t<u16, 0, 2, 0, 128><<<dim3(8, 32, g), 256, 0, stream>>>(
          wvt, h, Vtg, bv + (size_t)L * 4096, nullptr,
          4096, 1024, 1024, 1024, 1024, 1024, 1.f,
          g0, 1, 0, 1, 0, 0, 0, 1048576LL, 0, 4194304LL, 0);
      // attention over 8g (b,h) pairs, chunks of nc
      for (int c0 = 0; c0 < 8 * g; c0 += nc) {
        gemm_t<u16, 0, 0, 0, 128><<<dim3(8, 8, nc), 256, 0, stream>>>(
            Qg, Kg, Sc, nullptr, nullptr,
            1024, 1024, 512, 4096, 4096, 1024, qk_scale,
            c0, 8, 1, 1, 0,
            4194304LL, 512LL, 4194304LL, 512LL, 8388608LL, 1048576LL);
        sm_k<<<nc << 10, 256, 0, stream>>>(Sc, Pp);
        gemm_t<u16, 0, 0, 0, 128><<<dim3(4, 8, nc), 256, 0, stream>>>(
            Pp, Vtg, Og, nullptr, nullptr,
            1024, 512, 1024, 1024, 1024, 4096, 1.f,
            c0, 8, 0, 1, 1,
            8388608LL, 1048576LL, 4194304LL, 524288LL, 4194304LL, 512LL);
      }
      // x_g += O_g @ wo + bo  (BN=64 -> 1024 blocks)
      gemm_t<float, 0, 1, 1, 64><<<dim3(16, Mg >> 7), 256, 0, stream>>>(
          Og, wot, x + (size_t)g0 * 1048576, bo + (size_t)L * 1024,
          x + (size_t)g0 * 1048576,
          Mg, 1024, 4096, 4096, 4096, 1024, 1.f,
          0, 1, 0, 0, 0, 0, 0, 0, 0, 0, 0);
    }

    ln_k<<<8192, 256, 0, stream>>>(x, h, ln2g + L * 1024, ln2b + L * 1024);

    // ff = gelu(h @ w1 + b1)  (BN=64)
    gemm_t<u16, 1, 1, 0, 64><<<dim3(16, 64), 256, 0, stream>>>(
        h, w1t, ff, b1 + (size_t)L * 1024, nullptr,
        8192, 1024, 1024, 1024, 1024, 1024, 1.f,
        0, 1, 0, 0, 0, 0, 0, 0, 0, 0, 0);
    // x += ff @ w2 + b2  (last layer writes d_out directly)
    float* cdst = (L == 1) ? (float*)d_out : x;
    gemm_t<float, 0, 1, 1, 64><<<dim3(16, 64), 256, 0, stream>>>(
        ff, w2t, cdst, b2 + (size_t)L * 1024, x,
        8192, 1024, 1024, 1024, 1024, 1024, 1.f,
        0, 1, 0, 0, 0, 0, 0, 0, 0, 0, 0);
  }
}

// Round 9
// 1495.534 us; speedup vs baseline: 1.8283x; 1.0192x over previous
//
#include <hip/hip_runtime.h>

// BiTransformer fwd: B=8,S=1024,D=1024,H=8,DH=512,R=36,V=32002, 2 layers.
// Device I/O float32. Internal GEMM operands bf16.
// gemm8p: 256x256 tile, BK=64, 8 waves, counted-vmcnt(8) double-buffer pipeline
//         (raw s_barrier, never drains vmcnt to 0 mid-loop), XOR swizzle,
//         XCD block swizzle, setprio around MFMA.  [QKV, Vt, QK^T, PV]
// gemm_t<64>: 128x64 tile drain-loop (proven R8 config). [Oproj, FFN]
// launch_bounds note: (256,5/6) spilled in R7 (VGPR 64->48, 465MB WRITE). Keep (256,4).

using u16 = unsigned short;
typedef __attribute__((ext_vector_type(8))) short bf16x8;
typedef __attribute__((ext_vector_type(4))) float f32x4;

__device__ __forceinline__ float b2f(u16 u) {
  union { unsigned int i; float f; } v; v.i = ((unsigned int)u) << 16; return v.f;
}
__device__ __forceinline__ u16 f2b(float f) {
  union { float f; unsigned int i; } v; v.f = f;
  unsigned int i = v.i;
  return (u16)((i + 0x7FFFu + ((i >> 16) & 1u)) >> 16);
}
__device__ __forceinline__ float gelu_f(float x) {
  return 0.5f * x * (1.f + erff(x * 0.70710678118654752f));
}
__device__ __forceinline__ void async16(void* lds, const void* g) {
  __builtin_amdgcn_global_load_lds((const __attribute__((address_space(1))) void*)g,
                                   (__attribute__((address_space(3))) void*)lds, 16, 0, 0);
}
__device__ __forceinline__ void storeC(float* p, float v) { *p = v; }
__device__ __forceinline__ void storeC(u16* p, float v) { *p = f2b(v); }

// ---------------- embedding (f32 in, f32 out) ----------------
__global__ __launch_bounds__(256) void embed_k(
    const int* __restrict__ words, const float* __restrict__ img,
    const float* __restrict__ emb, const float* __restrict__ id2v,
    float* __restrict__ x)
{
  __shared__ float vs[36];
  int tok = blockIdx.x, b = tok >> 10, t = threadIdx.x;
  int wd = words[tok];
  if (t < 36) vs[t] = id2v[(size_t)wd * 36 + t];
  __syncthreads();
  bool any = false;
#pragma unroll
  for (int r = 0; r < 36; ++r) any = any || (vs[r] != 0.f);
#pragma unroll
  for (int i = 0; i < 4; ++i) {
    int d = t + (i << 8);
    float acc = 0.f;
    for (int r = 0; r < 36; ++r) {
      float vv = vs[r];
      if (vv != 0.f) acc += vv * img[((size_t)(b * 36 + r) << 10) + d];
    }
    float te = any ? 0.f : emb[((size_t)wd << 10) + d];
    x[((size_t)tok << 10) + d] = te + acc;
  }
}

// ---------------- layernorm (f32 in, bf16 out), D=1024 ----------------
__global__ __launch_bounds__(256) void ln_k(
    const float* __restrict__ x, u16* __restrict__ out,
    const float* __restrict__ g, const float* __restrict__ bb)
{
  __shared__ float red[4];
  int row = blockIdx.x, t = threadIdx.x;
  const float* xr = x + ((size_t)row << 10);
  float v[4], s = 0.f;
#pragma unroll
  for (int i = 0; i < 4; ++i) { v[i] = xr[t + (i << 8)]; s += v[i]; }
#pragma unroll
  for (int o = 32; o; o >>= 1) s += __shfl_xor(s, o, 64);
  if ((t & 63) == 0) red[t >> 6] = s;
  __syncthreads();
  s = red[0] + red[1] + red[2] + red[3];
  float mean = s * 0.0009765625f;
  float q = 0.f;
#pragma unroll
  for (int i = 0; i < 4; ++i) { float d = v[i] - mean; q += d * d; }
  __syncthreads();
#pragma unroll
  for (int o = 32; o; o >>= 1) q += __shfl_xor(q, o, 64);
  if ((t & 63) == 0) red[t >> 6] = q;
  __syncthreads();
  q = red[0] + red[1] + red[2] + red[3];
  float rstd = rsqrtf(q * 0.0009765625f + 1e-5f);
  u16* orow = out + ((size_t)row << 10);
#pragma unroll
  for (int i = 0; i < 4; ++i) {
    int d = t + (i << 8);
    orow[d] = f2b((v[i] - mean) * rstd * g[d] + bb[d]);
  }
}

// ------------- shifted softmax on bf16 scores: p = e^(s-m)/(1+sum), cols=1024 -------------
__global__ __launch_bounds__(256) void sm_k(const u16* __restrict__ S, u16* __restrict__ P)
{
  __shared__ float red[4];
  size_t row = blockIdx.x;
  int t = threadIdx.x;
  const u16* sr = S + (row << 10);
  ushort4 sv = *(const ushort4*)(sr + (t << 2));
  float v[4] = { b2f(sv.x), b2f(sv.y), b2f(sv.z), b2f(sv.w) };
  float m = fmaxf(fmaxf(v[0], v[1]), fmaxf(v[2], v[3]));
#pragma unroll
  for (int o = 32; o; o >>= 1) m = fmaxf(m, __shfl_xor(m, o, 64));
  if ((t & 63) == 0) red[t >> 6] = m;
  __syncthreads();
  m = fmaxf(fmaxf(red[0], red[1]), fmaxf(red[2], red[3]));
  float e[4], s = 0.f;
#pragma unroll
  for (int i = 0; i < 4; ++i) { e[i] = __expf(v[i] - m); s += e[i]; }
  __syncthreads();
#pragma unroll
  for (int o = 32; o; o >>= 1) s += __shfl_xor(s, o, 64);
  if ((t & 63) == 0) red[t >> 6] = s;
  __syncthreads();
  s = red[0] + red[1] + red[2] + red[3];
  float inv = 1.f / (1.f + s);
  ushort4 pv;
  pv.x = f2b(e[0] * inv); pv.y = f2b(e[1] * inv);
  pv.z = f2b(e[2] * inv); pv.w = f2b(e[3] * inv);
  *(ushort4*)(P + (row << 10) + (t << 2)) = pv;
}

// ------------- weight transpose + f32->bf16, 64x64 tiles -------------
__global__ __launch_bounds__(256) void tr_k(
    const float* __restrict__ src, u16* __restrict__ dst, int ls, int ld)
{
  __shared__ u16 tile[64][65];
  int c0 = blockIdx.x << 6, r0 = blockIdx.y << 6;
  int tx = threadIdx.x & 63, ty0 = threadIdx.x >> 6;
#pragma unroll
  for (int i = 0; i < 16; ++i) {
    int ty = (ty0 << 4) + i;
    tile[ty][tx] = f2b(src[(size_t)(r0 + ty) * ls + (c0 + tx)]);
  }
  __syncthreads();
#pragma unroll
  for (int i = 0; i < 16; ++i) {
    int ty = (ty0 << 4) + i;
    dst[(size_t)(c0 + ty) * ld + (r0 + tx)] = tile[tx][ty];
  }
}

// ======== gemm8p: C = act(scale*A@Bt^T + bias) [+resid], 256x256 tile ========
// BK=64, 8 waves (2Mx4N), wave tile 128x64. 128KB LDS, 2-deep counted-vmcnt
// pipeline: STAGE issues 8 global_load_lds/wave; loop waits vmcnt(8) (tile t
// landed, tile t+1 still in flight), raw s_barrier + sched_barrier(0) (block
// ds_read hoist past barrier), MFMA under setprio, lgkmcnt(0) fence + barrier,
// then restage the consumed buffer for tile t+2. Never drains vmcnt mid-loop.
template <typename CT, int ACT, int BIAS, int RESID>
__global__ __launch_bounds__(512, 1) void gemm8p(
    const u16* __restrict__ A, const u16* __restrict__ Bt,
    CT* __restrict__ C, const float* __restrict__ bias,
    const float* __restrict__ resid,
    int M, int N, int K, int lda, int ldb, int ldc, float scale,
    int zbase, int zdiv, int ga, int gb, int gc,
    long long aS1, long long aS2, long long bS1, long long bS2,
    long long cS1, long long cS2)
{
  __shared__ u16 lA[2][256 * 64];
  __shared__ u16 lB[2][256 * 64];
  // XCD-aware bijective remap of the (x,y) grid
  const int nwg = gridDim.x * gridDim.y;
  const int id = blockIdx.y * gridDim.x + blockIdx.x;
  const int qq = nwg >> 3, rr8 = nwg & 7;
  const int xcd = id & 7, off = id >> 3;
  const int swz = (xcd < rr8 ? xcd * (qq + 1) : rr8 * (qq + 1) + (xcd - rr8) * qq) + off;
  const int bx = swz % gridDim.x, by = swz / gridDim.x;

  long long lz = blockIdx.z;
  long long gz = zbase + lz;
  long long zA = ga ? gz : lz, zB = gb ? gz : lz, zC = gc ? gz : lz;
  size_t aOff = (size_t)((zA / zdiv) * aS1 + (zA % zdiv) * aS2);
  size_t bOff = (size_t)((zB / zdiv) * bS1 + (zB % zdiv) * bS2);
  size_t cOff = (size_t)((zC / zdiv) * cS1 + (zC % zdiv) * cS2);
  const int m0 = by << 8, n0 = bx << 8;
  const int tid = threadIdx.x, lane = tid & 63, w = tid >> 6;
  const int wm = w >> 2, wn = w & 3;         // 2x4 wave grid, wave tile 128x64
  const int srow8 = lane >> 3;               // staging row within 8-row slice
  const int schunk = (lane & 7) ^ srow8;     // inverse-swizzled source chunk
  const int fr = lane & 15, hi = lane >> 4;

  f32x4 acc[8][4];
#pragma unroll
  for (int mi = 0; mi < 8; ++mi)
#pragma unroll
    for (int ni = 0; ni < 4; ++ni) acc[mi][ni] = 0.f;

  const u16* Ab = A + aOff;
  const u16* Bb = Bt + bOff;

  // stage one 256x64 K-tile pair (A+B) into buf: 8 global_load_lds per wave
  auto STAGE = [&](int buf, int k0) {
#pragma unroll
    for (int s = 0; s < 4; ++s) {
      const int rb = (s << 6) + (w << 3);  // rows rb..rb+7
      async16(&lA[buf][rb << 6], Ab + (size_t)(m0 + rb + srow8) * lda + (k0 + (schunk << 3)));
      async16(&lB[buf][rb << 6], Bb + (size_t)(n0 + rb + srow8) * ldb + (k0 + (schunk << 3)));
    }
  };

  const int nt = K >> 6;
  STAGE(0, 0);
  STAGE(1, 64);
  for (int t = 0; t < nt; ++t) {
    const int cur = t & 1;
    if (t + 1 < nt) asm volatile("s_waitcnt vmcnt(8)" ::: "memory");
    else            asm volatile("s_waitcnt vmcnt(0)" ::: "memory");
    __builtin_amdgcn_s_barrier();
    __builtin_amdgcn_sched_barrier(0);  // keep ds_reads below the barrier
#pragma unroll
    for (int ks = 0; ks < 2; ++ks) {
      const int q = (ks << 2) + hi;  // K-chunk 0..7
      bf16x8 a8[8], b8[4];
#pragma unroll
      for (int mi = 0; mi < 8; ++mi) {
        const int R = (wm << 7) + (mi << 4) + fr;
        a8[mi] = *(const bf16x8*)&lA[cur][(R << 6) + ((q ^ (R & 7)) << 3)];
      }
#pragma unroll
      for (int ni = 0; ni < 4; ++ni) {
        const int R = (wn << 6) + (ni << 4) + fr;
        b8[ni] = *(const bf16x8*)&lB[cur][(R << 6) + ((q ^ (R & 7)) << 3)];
      }
      __builtin_amdgcn_s_setprio(1);
#pragma unroll
      for (int mi = 0; mi < 8; ++mi)
#pragma unroll
        for (int ni = 0; ni < 4; ++ni)
          acc[mi][ni] = __builtin_amdgcn_mfma_f32_16x16x32_bf16(a8[mi], b8[ni], acc[mi][ni], 0, 0, 0);
      __builtin_amdgcn_s_setprio(0);
    }
    if (t + 2 < nt) {
      asm volatile("s_waitcnt lgkmcnt(0)" ::: "memory");  // all reads of buf[cur] done
      __builtin_amdgcn_s_barrier();
      __builtin_amdgcn_sched_barrier(0);
      STAGE(cur, (t + 2) << 6);  // refill consumed buffer; lands during tile t+1 compute
    }
  }

  const int r4 = hi << 2, cc = fr;
#pragma unroll
  for (int mi = 0; mi < 8; ++mi) {
#pragma unroll
    for (int ni = 0; ni < 4; ++ni) {
      const int col = n0 + (wn << 6) + (ni << 4) + cc;
      float bcol = 0.f;
      if (BIAS == 1) bcol = bias[col];
#pragma unroll
      for (int j = 0; j < 4; ++j) {
        const int row = m0 + (wm << 7) + (mi << 4) + r4 + j;
        float v = acc[mi][ni][j] * scale + bcol;
        if (BIAS == 2) v += bias[row];
        if (ACT == 1) v = gelu_f(v);
        const size_t idx = cOff + (size_t)row * ldc + col;
        if (RESID) v += resid[idx];
        storeC(&C[idx], v);
      }
    }
  }
}

// ---------------- gemm_t<BN>: 128xBN drain-loop tile (Oproj/FFN shapes) ----------------
template <typename CT, int ACT, int BIAS, int RESID, int BN>
__global__ __launch_bounds__(256, 4) void gemm_t(
    const u16* __restrict__ A, const u16* __restrict__ Bt,
    CT* __restrict__ C, const float* __restrict__ bias,
    const float* __restrict__ resid,
    int M, int N, int K, int lda, int ldb, int ldc, float scale,
    int zbase, int zdiv, int ga, int gb, int gc,
    long long aS1, long long aS2, long long bS1, long long bS2,
    long long cS1, long long cS2)
{
  constexpr int NACC = BN / 32;
  __shared__ u16 lA[128 * 64];
  __shared__ u16 lB[BN * 64];
  const int nwg = gridDim.x * gridDim.y;
  const int id = blockIdx.y * gridDim.x + blockIdx.x;
  const int qq = nwg >> 3, rr8 = nwg & 7;
  const int xcd = id & 7, off = id >> 3;
  const int swz = (xcd < rr8 ? xcd * (qq + 1) : rr8 * (qq + 1) + (xcd - rr8) * qq) + off;
  const int bx = swz % gridDim.x, by = swz / gridDim.x;

  long long lz = blockIdx.z;
  long long gz = zbase + lz;
  long long zA = ga ? gz : lz, zB = gb ? gz : lz, zC = gc ? gz : lz;
  size_t aOff = (size_t)((zA / zdiv) * aS1 + (zA % zdiv) * aS2);
  size_t bOff = (size_t)((zB / zdiv) * bS1 + (zB % zdiv) * bS2);
  size_t cOff = (size_t)((zC / zdiv) * cS1 + (zC % zdiv) * cS2);
  const int m0 = by << 7, n0 = bx * BN;
  const int tid = threadIdx.x, lane = tid & 63, w = tid >> 6;
  const int wm = w >> 1, wn = w & 1;
  const int srow8 = lane >> 3;
  const int schunk = (lane & 7) ^ srow8;
  const int fr = lane & 15, hi = lane >> 4;

  f32x4 acc[4][NACC];
#pragma unroll
  for (int mi = 0; mi < 4; ++mi)
#pragma unroll
    for (int ni = 0; ni < NACC; ++ni) acc[mi][ni] = 0.f;

  const u16* Ab = A + aOff;
  const u16* Bb = Bt + bOff;

  for (int k0 = 0; k0 < K; k0 += 64) {
#pragma unroll
    for (int s = 0; s < 4; ++s) {
      const int rb = (s << 5) + (w << 3);
      async16(&lA[rb << 6], Ab + (size_t)(m0 + rb + srow8) * lda + (k0 + (schunk << 3)));
    }
#pragma unroll
    for (int s = 0; s < BN / 32; ++s) {
      const int rb = (s << 5) + (w << 3);
      async16(&lB[rb << 6], Bb + (size_t)(n0 + rb + srow8) * ldb + (k0 + (schunk << 3)));
    }
    __syncthreads();
#pragma unroll
    for (int ks = 0; ks < 2; ++ks) {
      const int q = (ks << 2) + hi;
      bf16x8 a8[4], b8[NACC];
#pragma unroll
      for (int mi = 0; mi < 4; ++mi) {
        const int R = (wm << 6) + (mi << 4) + fr;
        a8[mi] = *(const bf16x8*)&lA[(R << 6) + ((q ^ (R & 7)) << 3)];
      }
#pragma unroll
      for (int ni = 0; ni < NACC; ++ni) {
        const int R = wn * (BN / 2) + (ni << 4) + fr;
        b8[ni] = *(const bf16x8*)&lB[(R << 6) + ((q ^ (R & 7)) << 3)];
      }
#pragma unroll
      for (int mi = 0; mi < 4; ++mi)
#pragma unroll
        for (int ni = 0; ni < NACC; ++ni)
          acc[mi][ni] = __builtin_amdgcn_mfma_f32_16x16x32_bf16(a8[mi], b8[ni], acc[mi][ni], 0, 0, 0);
    }
    __syncthreads();
  }

  const int r4 = hi << 2, cc = fr;
#pragma unroll
  for (int mi = 0; mi < 4; ++mi) {
#pragma unroll
    for (int ni = 0; ni < NACC; ++ni) {
      const int col = n0 + wn * (BN / 2) + (ni << 4) + cc;
      float bcol = 0.f;
      if (BIAS == 1) bcol = bias[col];
#pragma unroll
      for (int j = 0; j < 4; ++j) {
        const int row = m0 + (wm << 6) + (mi << 4) + r4 + j;
        float v = acc[mi][ni][j] * scale + bcol;
        if (BIAS == 2) v += bias[row];
        if (ACT == 1) v = gelu_f(v);
        const size_t idx = cOff + (size_t)row * ldc + col;
        if (RESID) v += resid[idx];
        storeC(&C[idx], v);
      }
    }
  }
}

extern "C" void kernel_launch(void* const* d_in, const int* in_sizes, int n_in,
                              void* d_out, int out_size, void* d_ws, size_t ws_size,
                              hipStream_t stream)
{
  (void)in_sizes; (void)n_in; (void)out_size;
  const int*   pre_words = (const int*)d_in[0];
  const float* img  = (const float*)d_in[1];
  const float* emb  = (const float*)d_in[2];
  const float* id2v = (const float*)d_in[3];
  const float* wq = (const float*)d_in[4];  const float* bq = (const float*)d_in[5];
  const float* wk = (const float*)d_in[6];  const float* bk = (const float*)d_in[7];
  const float* wv = (const float*)d_in[8];  const float* bv = (const float*)d_in[9];
  const float* wo = (const float*)d_in[10]; const float* bo = (const float*)d_in[11];
  const float* w1 = (const float*)d_in[12]; const float* b1 = (const float*)d_in[13];
  const float* w2 = (const float*)d_in[14]; const float* b2 = (const float*)d_in[15];
  const float* ln1g = (const float*)d_in[16]; const float* ln1b = (const float*)d_in[17];
  const float* ln2g = (const float*)d_in[18]; const float* ln2b = (const float*)d_in[19];

  const size_t FIXED = 88080384 + (size_t)(1 << 16);
  int g = 1;
  for (int c = 8; c >= 1; c >>= 1)
    if (FIXED + (size_t)c * 33554432 + 4194304 <= ws_size) { g = c; break; }
  int nc = 1;
  int ncmax = 8 * g > 32 ? 32 : 8 * g;
  for (int c = ncmax; c >= 1; c >>= 1)
    if (FIXED + (size_t)g * 33554432 + (size_t)c * 4194304 <= ws_size) { nc = c; break; }

  char* p = (char*)d_ws;
  auto alloc = [&](size_t bytes) -> void* {
    void* r = (void*)p; p += (bytes + 255) & ~(size_t)255; return r;
  };
  float* x  = (float*)alloc((size_t)8192 * 1024 * 4);     // residual f32 (32MB)
  u16* h    = (u16*)alloc((size_t)8192 * 1024 * 2);       // LN output (16MB)
  u16* Qg   = (u16*)alloc((size_t)g * 1024 * 4096 * 2);   // group Q
  u16* Og   = (u16*)alloc((size_t)g * 1024 * 4096 * 2);   // group O
  u16* ff   = Qg;                                         // FFN mid reuses Qg[+Og]
  u16* Kg   = (u16*)alloc((size_t)g * 1024 * 4096 * 2);   // group K
  u16* Vtg  = (u16*)alloc((size_t)g * 4096 * 1024 * 2);   // group V^T (per batch (HD,S))
  u16* wqt  = (u16*)alloc((size_t)4096 * 1024 * 2);
  u16* wkt  = (u16*)alloc((size_t)4096 * 1024 * 2);
  u16* wvt  = (u16*)alloc((size_t)4096 * 1024 * 2);
  u16* wot  = (u16*)alloc((size_t)1024 * 4096 * 2);
  u16* w1t  = (u16*)alloc((size_t)1024 * 1024 * 2);
  u16* w2t  = (u16*)alloc((size_t)1024 * 1024 * 2);
  u16* Sc   = (u16*)alloc((size_t)nc << 21);   // nc * 1M bf16 scores
  u16* Pp   = (u16*)alloc((size_t)nc << 21);   // nc * 1M bf16 probs

  embed_k<<<8192, 256, 0, stream>>>(pre_words, img, emb, id2v, x);

  const float qk_scale = 0.044194173824159216f;  // 1/sqrt(512)
  for (int L = 0; L < 2; ++L) {
    const float* WQ = wq + (size_t)L * 1024 * 4096;
    const float* WK = wk + (size_t)L * 1024 * 4096;
    const float* WV = wv + (size_t)L * 1024 * 4096;
    const float* WO = wo + (size_t)L * 4096 * 1024;
    const float* W1 = w1 + (size_t)L * 1024 * 1024;
    const float* W2 = w2 + (size_t)L * 1024 * 1024;

    tr_k<<<dim3(64, 16), 256, 0, stream>>>(WQ, wqt, 4096, 1024);
    tr_k<<<dim3(64, 16), 256, 0, stream>>>(WK, wkt, 4096, 1024);
    tr_k<<<dim3(64, 16), 256, 0, stream>>>(WV, wvt, 4096, 1024);
    tr_k<<<dim3(16, 64), 256, 0, stream>>>(WO, wot, 1024, 4096);
    tr_k<<<dim3(16, 16), 256, 0, stream>>>(W1, w1t, 1024, 1024);
    tr_k<<<dim3(16, 16), 256, 0, stream>>>(W2, w2t, 1024, 1024);

    ln_k<<<8192, 256, 0, stream>>>(x, h, ln1g + L * 1024, ln1b + L * 1024);

    for (int g0 = 0; g0 < 8; g0 += g) {
      const u16* hg = h + (size_t)g0 * 1048576;
      const int Mg = 1024 * g;
      // Qg / Kg = h_g @ w + bias : (Mg, 4096), 256^2 pipelined tiles
      gemm8p<u16, 0, 1, 0><<<dim3(16, Mg >> 8), 512, 0, stream>>>(
          hg, wqt, Qg, bq + (size_t)L * 4096, nullptr,
          Mg, 4096, 1024, 1024, 1024, 4096, 1.f,
          0, 1, 0, 0, 0, 0, 0, 0, 0, 0, 0);
      gemm8p<u16, 0, 1, 0><<<dim3(16, Mg >> 8), 512, 0, stream>>>(
          hg, wkt, Kg, bk + (size_t)L * 4096, nullptr,
          Mg, 4096, 1024, 1024, 1024, 4096, 1.f,
          0, 1, 0, 0, 0, 0, 0, 0, 0, 0, 0);
      // Vtg[b][hd][s] = (h_b @ wv + bv)^T : A=wvt, B=h_b, row-bias, z=batch
      gemm8p<u16, 0, 2, 0><<<dim3(4, 16, g), 512, 0, stream>>>(
          wvt, h, Vtg, bv + (size_t)L * 4096, nullptr,
          4096, 1024, 1024, 1024, 1024, 1024, 1.f,
          g0, 1, 0, 1, 0, 0, 0, 1048576LL, 0, 4194304LL, 0);
      // attention over 8g (b,h) pairs, chunks of nc
      for (int c0 = 0; c0 < 8 * g; c0 += nc) {
        gemm8p<u16, 0, 0, 0><<<dim3(4, 4, nc), 512, 0, stream>>>(
            Qg, Kg, Sc, nullptr, nullptr,
            1024, 1024, 512, 4096, 4096, 1024, qk_scale,
            c0, 8, 1, 1, 0,
            4194304LL, 512LL, 4194304LL, 512LL, 8388608LL, 1048576LL);
        sm_k<<<nc << 10, 256, 0, stream>>>(Sc, Pp);
        gemm8p<u16, 0, 0, 0><<<dim3(2, 4, nc), 512, 0, stream>>>(
            Pp, Vtg, Og, nullptr, nullptr,
            1024, 512, 1024, 1024, 1024, 4096, 1.f,
            c0, 8, 0, 1, 1,
            8388608LL, 1048576LL, 4194304LL, 524288LL, 4194304LL, 512LL);
      }
      // x_g += O_g @ wo + bo  (BN=64 -> 1024 blocks)
      gemm_t<float, 0, 1, 1, 64><<<dim3(16, Mg >> 7), 256, 0, stream>>>(
          Og, wot, x + (size_t)g0 * 1048576, bo + (size_t)L * 1024,
          x + (size_t)g0 * 1048576,
          Mg, 1024, 4096, 4096, 4096, 1024, 1.f,
          0, 1, 0, 0, 0, 0, 0, 0, 0, 0, 0);
    }

    ln_k<<<8192, 256, 0, stream>>>(x, h, ln2g + L * 1024, ln2b + L * 1024);

    // ff = gelu(h @ w1 + b1)  (BN=64)
    gemm_t<u16, 1, 1, 0, 64><<<dim3(16, 64), 256, 0, stream>>>(
        h, w1t, ff, b1 + (size_t)L * 1024, nullptr,
        8192, 1024, 1024, 1024, 1024, 1024, 1.f,
        0, 1, 0, 0, 0, 0, 0, 0, 0, 0, 0);
    // x += ff @ w2 + b2  (last layer writes d_out directly)
    float* cdst = (L == 1) ? (float*)d_out : x;
    gemm_t<float, 0, 1, 1, 64><<<dim3(16, 64), 256, 0, stream>>>(
        ff, w2t, cdst, b2 + (size_t)L * 1024, x,
        8192, 1024, 1024, 1024, 1024, 1024, 1.f,
        0, 1, 0, 0, 0, 0, 0, 0, 0, 0, 0);
  }
}